// Round 2
// baseline (319.626 us; speedup 1.0000x reference)
//
#include <hip/hip_runtime.h>
#include <math.h>

// Problem constants (from reference): B=64, C=64, L=8192, fp32.
#define BB 64
#define CC 64
#define LL 8192
#define EPS_F 1.1920928955078125e-07f  // np.finfo(np.float32).eps

#define GROUPS 16                // blocks per batch
#define ROWS_PER_BLK 4           // CC / GROUPS
#define NBLK (BB * GROUPS)       // 1024 blocks total
#define ROW4 (LL / 4)            // 2048 float4 per row

typedef float f4 __attribute__((ext_vector_type(4)));
typedef int   i4 __attribute__((ext_vector_type(4)));

// d_ws layout (first 768 B zeroed by hipMemsetAsync each launch):
//   ws[0..63]    float  batch sums      (atomicAdd accumulated)
//   ws[64..127]  float  batch sumsqs    (atomicAdd accumulated)
//   ws[128..191] int    arrival flags   (release-incremented to GROUPS)

// ---------------------------------------------------------------------------
// Single-kernel pipeline. Block blk = b*16 + t owns rows c = 4t..4t+3 of
// batch b. Phase 1: masked prefix partial -> device-scope atomics. Overlap
// window: idx conversion. Spin (per-batch, not global): batches proceed
// independently, so phase-2 writes of early batches overlap phase-1 reads of
// late ones -- HBM stays saturated, no global drain, one launch.
// Phase 2: normalize own rows (L2/L3-hot from phase 1) with NT stores.
// ---------------------------------------------------------------------------
__global__ __launch_bounds__(256) void tln_onepass(
    const float* __restrict__ data,
    const int*   __restrict__ zero_pos,
    const i4*    __restrict__ idxes,
    float*       __restrict__ ws,
    f4*          __restrict__ out4,
    f4*          __restrict__ out_idx,
    float*       __restrict__ out_zp)
{
    const int blk = blockIdx.x;
    const int tid = threadIdx.x;           // 0..255
    const int b   = blk >> 4;
    const int t   = blk & 15;
    const int zp  = zero_pos[b];
    const int nv  = zp >> 2;               // full float4's per row
    const int rem = zp & 3;

    float* sums  = ws;
    float* sqs   = ws + 64;
    int*   flags = (int*)(ws + 128);

    const float* base = data + ((size_t)b * CC + (size_t)t * ROWS_PER_BLK) * LL;

    // ---- Phase 1: prefix partial over 4 rows ----
    float sum = 0.0f, sq = 0.0f;
    #pragma unroll
    for (int r = 0; r < ROWS_PER_BLK; ++r) {
        const float* rowp = base + (size_t)r * LL;
        const f4* row4 = (const f4*)rowp;       // L=8192 -> 16B aligned
        for (int i = tid; i < nv; i += 256) {
            f4 v = row4[i];
            sum += v.x + v.y + v.z + v.w;
            sq  += v.x * v.x + v.y * v.y + v.z * v.z + v.w * v.w;
        }
        if (rem && tid == 0) {                  // <=3 scalar leftovers per row
            for (int e = 0; e < rem; ++e) {
                float v = rowp[nv * 4 + e];
                sum += v; sq += v * v;
            }
        }
    }

    // block reduce: wave shfl + LDS across 4 waves
    #pragma unroll
    for (int off = 32; off > 0; off >>= 1) {
        sum += __shfl_down(sum, off);
        sq  += __shfl_down(sq, off);
    }
    __shared__ float lsum[4], lsq[4];
    __shared__ float s_m, s_inv;
    const int wave = tid >> 6;
    const int lane = tid & 63;
    if (lane == 0) { lsum[wave] = sum; lsq[wave] = sq; }
    __syncthreads();
    if (tid == 0) {
        float bs = lsum[0] + lsum[1] + lsum[2] + lsum[3];
        float bq = lsq[0] + lsq[1] + lsq[2] + lsq[3];
        atomicAdd(&sums[b], bs);               // device-scope by default
        atomicAdd(&sqs[b],  bq);
        __hip_atomic_fetch_add(&flags[b], 1, __ATOMIC_RELEASE,
                               __HIP_MEMORY_SCOPE_AGENT);
    }

    // ---- Overlap window: idx conversion (128 i4 per block) + zp out ----
    if (tid < 128) {
        const int ii = blk * 128 + tid;        // covers exactly B*L/4 = 131072
        i4 v = idxes[ii];
        f4 o = __builtin_convertvector(v, f4);
        __builtin_nontemporal_store(o, out_idx + ii);
    }
    if (blk == 0 && tid < BB) out_zp[tid] = (float)zero_pos[tid];

    // ---- Per-batch spin: wait for this batch's 16 partials ----
    if (tid == 0) {
        while (__hip_atomic_load(&flags[b], __ATOMIC_ACQUIRE,
                                 __HIP_MEMORY_SCOPE_AGENT) != GROUPS)
            __builtin_amdgcn_s_sleep(1);
        // coherent (device-scope) loads: sums may live in another XCD's L2
        float S = __hip_atomic_load(&sums[b], __ATOMIC_RELAXED,
                                    __HIP_MEMORY_SCOPE_AGENT);
        float Q = __hip_atomic_load(&sqs[b], __ATOMIC_RELAXED,
                                    __HIP_MEMORY_SCOPE_AGENT);
        const float cnt  = (float)CC * (float)zp;
        const float mean = S / cnt;
        const float var  = (Q - cnt * mean * mean) / (cnt - 1.0f);
        s_m   = mean;
        s_inv = 1.0f / (sqrtf(var) + EPS_F);
    }
    __syncthreads();
    const float m = s_m, inv = s_inv;

    // ---- Phase 2: normalize own 4 rows (L2/L3-hot), NT stores ----
    const f4* base4 = (const f4*)base;
    const size_t obase = ((size_t)b * CC + (size_t)t * ROWS_PER_BLK) * ROW4;
    #pragma unroll
    for (int r = 0; r < ROWS_PER_BLK; ++r) {
        #pragma unroll
        for (int k = 0; k < 8; ++k) {
            const int i = r * ROW4 + k * 256 + tid;
            f4 v = base4[i];
            f4 o = (v - m) * inv;
            __builtin_nontemporal_store(o, out4 + obase + i);
        }
    }
}

extern "C" void kernel_launch(void* const* d_in, const int* in_sizes, int n_in,
                              void* d_out, int out_size, void* d_ws, size_t ws_size,
                              hipStream_t stream) {
    const float* data    = (const float*)d_in[0];
    const int* idxes     = (const int*)d_in[1];
    const int* zero_pos  = (const int*)d_in[2];

    float* out_data = (float*)d_out;                        // B*C*L
    float* out_idx  = out_data + (size_t)BB * CC * LL;      // B*L
    float* out_zp   = out_idx + (size_t)BB * LL;            // B

    // zero the 768 B of accumulators + flags (graph-capture-safe)
    hipMemsetAsync(d_ws, 0, 192 * sizeof(float), stream);

    tln_onepass<<<NBLK, 256, 0, stream>>>(
        data, zero_pos, (const i4*)idxes, (float*)d_ws,
        (f4*)out_data, (f4*)out_idx, out_zp);
}

// Round 3
// 317.182 us; speedup vs baseline: 1.0077x; 1.0077x over previous
//
#include <hip/hip_runtime.h>
#include <math.h>

// Problem constants (from reference): B=64, C=64, L=8192, fp32.
#define BB 64
#define CC 64
#define LL 8192
#define EPS_F 1.1920928955078125e-07f  // np.finfo(np.float32).eps

#define GROUPS 16                // blocks per batch
#define ROWS_PER_BLK 4           // CC / GROUPS
#define NBLK (BB * GROUPS)       // 1024 blocks total
#define ROW4 (LL / 4)            // 2048 float4 per row

typedef float f4 __attribute__((ext_vector_type(4)));
typedef int   i4 __attribute__((ext_vector_type(4)));

union pk64 { unsigned long long u; struct { float x, y; } f; };

// d_ws layout (first 768 B zeroed by hipMemsetAsync each launch):
//   [0,   512)  u64 ready[64]   packed {mean, inv}; 0 == not ready (inv>0 always)
//   [512, 768)  int cnt[64]     arrival counters (ACQ_REL incremented)
//   [768, 8960) u64 partials[1024]  per-block packed {sum, sumsq} (all overwritten)

// ---------------------------------------------------------------------------
// One-pass pipeline, invalidation-free sync. Block blk = b*16 + t owns rows
// 4t..4t+3 of batch b.
//  Phase 1: prefix partial (4 parallel row streams) -> relaxed u64 slot store,
//           one ACQ_REL counter RMW. Last arriver gathers 16 slots, computes
//           {mean, inv}, publishes packed u64 (release).
//  Overlap: idx conversion while stats propagate.
//  Gate:    relaxed-load spin on ready[b] -- the VALUE is the data, so no
//           acquire/buffer_inv per poll (round-2's 4x rate collapse).
//  Phase 2: normalize own rows (IF$-hot from phase 1), 8 loads in flight,
//           NT stores so the output stream doesn't evict cached input.
// ---------------------------------------------------------------------------
__global__ __launch_bounds__(256) void tln_onepass(
    const float* __restrict__ data,
    const int*   __restrict__ zero_pos,
    const i4*    __restrict__ idxes,
    unsigned long long* __restrict__ ready,     // [64]
    int*                __restrict__ cnt,       // [64]
    unsigned long long* __restrict__ partials,  // [1024]
    f4*          __restrict__ out4,
    f4*          __restrict__ out_idx,
    float*       __restrict__ out_zp)
{
    const int blk = blockIdx.x;
    const int tid = threadIdx.x;           // 0..255
    const int b   = blk >> 4;
    const int t   = blk & 15;
    const int zp  = zero_pos[b];
    const int nv  = zp >> 2;               // full float4's per row
    const int rem = zp & 3;

    const float* base = data + ((size_t)b * CC + (size_t)t * ROWS_PER_BLK) * LL;
    const f4* r0 = (const f4*)(base);
    const f4* r1 = (const f4*)(base + (size_t)LL);
    const f4* r2 = (const f4*)(base + 2 * (size_t)LL);
    const f4* r3 = (const f4*)(base + 3 * (size_t)LL);

    // ---- Phase 1: 4 independent row streams (4 loads in flight) ----
    float s0 = 0.f, s1 = 0.f, s2 = 0.f, s3 = 0.f;
    float q0 = 0.f, q1 = 0.f, q2 = 0.f, q3 = 0.f;
    for (int i = tid; i < nv; i += 256) {
        f4 a = r0[i], c = r1[i], d = r2[i], e = r3[i];
        s0 += a.x + a.y + a.z + a.w;  q0 += a.x*a.x + a.y*a.y + a.z*a.z + a.w*a.w;
        s1 += c.x + c.y + c.z + c.w;  q1 += c.x*c.x + c.y*c.y + c.z*c.z + c.w*c.w;
        s2 += d.x + d.y + d.z + d.w;  q2 += d.x*d.x + d.y*d.y + d.z*d.z + d.w*d.w;
        s3 += e.x + e.y + e.z + e.w;  q3 += e.x*e.x + e.y*e.y + e.z*e.z + e.w*e.w;
    }
    if (rem && tid < 12) {                 // tail: row = tid&3, elem = tid>>2
        const int rr = tid & 3, e = tid >> 2;
        if (e < rem) {
            float v = base[(size_t)rr * LL + nv * 4 + e];
            s0 += v; q0 += v * v;
        }
    }
    float sum = (s0 + s1) + (s2 + s3);
    float sq  = (q0 + q1) + (q2 + q3);

    // block reduce: wave shfl + LDS across 4 waves
    #pragma unroll
    for (int off = 32; off > 0; off >>= 1) {
        sum += __shfl_down(sum, off);
        sq  += __shfl_down(sq, off);
    }
    __shared__ float lsum[4], lsq[4];
    __shared__ float s_m, s_inv;
    const int wave = tid >> 6;
    const int lane = tid & 63;
    if (lane == 0) { lsum[wave] = sum; lsq[wave] = sq; }
    __syncthreads();
    if (tid == 0) {
        pk64 p;
        p.f.x = lsum[0] + lsum[1] + lsum[2] + lsum[3];
        p.f.y = lsq[0]  + lsq[1]  + lsq[2]  + lsq[3];
        __hip_atomic_store(&partials[blk], p.u, __ATOMIC_RELAXED,
                           __HIP_MEMORY_SCOPE_AGENT);
        const int old = __hip_atomic_fetch_add(&cnt[b], 1, __ATOMIC_ACQ_REL,
                                               __HIP_MEMORY_SCOPE_AGENT);
        if (old == GROUPS - 1) {           // last arriver: gather + publish
            float S = 0.f, Q = 0.f;
            #pragma unroll
            for (int g = 0; g < GROUPS; ++g) {
                pk64 r_;
                r_.u = __hip_atomic_load(&partials[(b << 4) + g], __ATOMIC_RELAXED,
                                         __HIP_MEMORY_SCOPE_AGENT);
                S += r_.f.x; Q += r_.f.y;
            }
            const float cf   = (float)CC * (float)zp;
            const float mean = S / cf;
            const float var  = (Q - cf * mean * mean) / (cf - 1.0f);
            pk64 o;
            o.f.x = mean;
            o.f.y = 1.0f / (sqrtf(var) + EPS_F);   // > 0 always => u64 != 0
            __hip_atomic_store(&ready[b], o.u, __ATOMIC_RELEASE,
                               __HIP_MEMORY_SCOPE_AGENT);
        }
    }

    // ---- Overlap window: idx conversion (128 i4 per block) + zp out ----
    if (tid < 128) {
        const int ii = blk * 128 + tid;    // covers exactly B*L/4 = 131072
        i4 v = idxes[ii];
        f4 o = __builtin_convertvector(v, f4);
        __builtin_nontemporal_store(o, out_idx + ii);
    }
    if (blk == 0 && tid < BB) out_zp[tid] = (float)zero_pos[tid];

    // ---- Gate: relaxed-load spin; loaded value IS {mean, inv} ----
    if (tid == 0) {
        pk64 r_;
        for (;;) {
            r_.u = __hip_atomic_load(&ready[b], __ATOMIC_RELAXED,
                                     __HIP_MEMORY_SCOPE_AGENT);
            if (r_.u != 0ull) break;
            __builtin_amdgcn_s_sleep(16);
        }
        s_m = r_.f.x; s_inv = r_.f.y;
    }
    __syncthreads();
    const float m = s_m, inv = s_inv;

    // ---- Phase 2: normalize own 4 rows, 8 loads in flight, NT stores ----
    const f4* base4 = (const f4*)base;
    const size_t obase = ((size_t)b * CC + (size_t)t * ROWS_PER_BLK) * ROW4;
    #pragma unroll
    for (int r = 0; r < ROWS_PER_BLK; ++r) {
        f4 v[8];
        #pragma unroll
        for (int k = 0; k < 8; ++k)
            v[k] = base4[(size_t)r * ROW4 + k * 256 + tid];
        #pragma unroll
        for (int k = 0; k < 8; ++k) {
            f4 o = (v[k] - m) * inv;
            __builtin_nontemporal_store(o, out4 + obase + (size_t)r * ROW4 + k * 256 + tid);
        }
    }
}

extern "C" void kernel_launch(void* const* d_in, const int* in_sizes, int n_in,
                              void* d_out, int out_size, void* d_ws, size_t ws_size,
                              hipStream_t stream) {
    const float* data    = (const float*)d_in[0];
    const int* idxes     = (const int*)d_in[1];
    const int* zero_pos  = (const int*)d_in[2];

    float* out_data = (float*)d_out;                        // B*C*L
    float* out_idx  = out_data + (size_t)BB * CC * LL;      // B*L
    float* out_zp   = out_idx + (size_t)BB * LL;            // B

    unsigned long long* ready    = (unsigned long long*)d_ws;          // 512 B
    int*                cnt      = (int*)((char*)d_ws + 512);          // 256 B
    unsigned long long* partials = (unsigned long long*)((char*)d_ws + 768);

    // zero ready + cnt only (768 B); partials are all overwritten
    hipMemsetAsync(d_ws, 0, 768, stream);

    tln_onepass<<<NBLK, 256, 0, stream>>>(
        data, zero_pos, (const i4*)idxes, ready, cnt, partials,
        (f4*)out_data, (f4*)out_idx, out_zp);
}